// Round 14
// baseline (1055.263 us; speedup 1.0000x reference)
//
#include <hip/hip_runtime.h>
#include <cstdint>
#include <cstddef>

#define N_TOK 8192
#define DIM   1024
#define NEXP  8
#define HID   4096
#define WELEM 4194304ull   // D*H elements per expert matrix

typedef __attribute__((ext_vector_type(8))) short short8v;
typedef __attribute__((ext_vector_type(4))) float f32x4;

__device__ __forceinline__ unsigned short f2bf(float f) {
  unsigned u = __builtin_bit_cast(unsigned, f);
  u += 0x7fffu + ((u >> 16) & 1u);     // RNE
  return (unsigned short)(u >> 16);
}

__device__ __forceinline__ void gload16(const void* g, void* l) {
  __builtin_amdgcn_global_load_lds(
      (const __attribute__((address_space(1))) void*)g,
      (__attribute__((address_space(3))) void*)l, 16, 0, 0);
}

// counted-vmcnt sync primitives (T4): loads stay in flight across barriers.
// sched_barrier(0) after each pins compiler ordering (rule #18).
#define VMW8 do { asm volatile("s_waitcnt vmcnt(8)" ::: "memory"); \
                  __builtin_amdgcn_sched_barrier(0); } while (0)
#define VMW0 do { asm volatile("s_waitcnt vmcnt(0)" ::: "memory"); \
                  __builtin_amdgcn_sched_barrier(0); } while (0)
#define BARR do { __builtin_amdgcn_s_barrier(); \
                  __builtin_amdgcn_sched_barrier(0); } while (0)

// ---------------- x fp32 -> bf16 ----------------
__global__ void convert_x_k(const float* __restrict__ x, unsigned short* __restrict__ xb) {
  size_t i = ((size_t)blockIdx.x * 256 + threadIdx.x) * 8;
  float4 a = *(const float4*)(x + i);
  float4 b = *(const float4*)(x + i + 4);
  short8v v;
  v[0] = (short)f2bf(a.x); v[1] = (short)f2bf(a.y); v[2] = (short)f2bf(a.z); v[3] = (short)f2bf(a.w);
  v[4] = (short)f2bf(b.x); v[5] = (short)f2bf(b.y); v[6] = (short)f2bf(b.z); v[7] = (short)f2bf(b.w);
  *(short8v*)(xb + i) = v;
}

// ---------------- gate: fp32 logits, top-2, softmax (NO atomics) ----------------
__global__ void gate2_k(const float* __restrict__ x, const float* __restrict__ gw,
                        const float* __restrict__ gb, int* __restrict__ tassign,
                        float2* __restrict__ tprob) {
  int lane = threadIdx.x & 63, wid = threadIdx.x >> 6;
  int t = blockIdx.x * 4 + wid;
  const float* xr = x + (size_t)t * DIM;
  float acc[NEXP];
#pragma unroll
  for (int e = 0; e < NEXP; ++e) acc[e] = 0.f;
#pragma unroll
  for (int j = 0; j < DIM / 256; ++j) {
    int d0 = j * 256 + lane * 4;
    float4 xv = *(const float4*)(xr + d0);
    const float* gp = gw + (size_t)d0 * NEXP;
#pragma unroll
    for (int c = 0; c < 4; ++c) {
      float xs = (c == 0) ? xv.x : (c == 1) ? xv.y : (c == 2) ? xv.z : xv.w;
      float4 g0 = *(const float4*)(gp + c * NEXP);
      float4 g1 = *(const float4*)(gp + c * NEXP + 4);
      acc[0] += xs * g0.x; acc[1] += xs * g0.y; acc[2] += xs * g0.z; acc[3] += xs * g0.w;
      acc[4] += xs * g1.x; acc[5] += xs * g1.y; acc[6] += xs * g1.z; acc[7] += xs * g1.w;
    }
  }
#pragma unroll
  for (int e = 0; e < NEXP; ++e) {
    float v = acc[e];
#pragma unroll
    for (int s = 1; s < 64; s <<= 1) v += __shfl_xor(v, s);
    acc[e] = v;
  }
  if (lane == 0) {
    float lg[NEXP];
#pragma unroll
    for (int e = 0; e < NEXP; ++e) lg[e] = acc[e] + gb[e];
    int i0 = 0;
#pragma unroll
    for (int e = 1; e < NEXP; ++e) if (lg[e] > lg[i0]) i0 = e;
    int i1 = -1;
#pragma unroll
    for (int e = 0; e < NEXP; ++e) if (e != i0 && (i1 < 0 || lg[e] > lg[i1])) i1 = e;
    float ex = expf(lg[i1] - lg[i0]);       // <= 1
    float p0 = 1.f / (1.f + ex);
    float p1 = ex * p0;
    tassign[t] = i0 | (i1 << 8);
    tprob[t] = make_float2(p0, p1);
  }
}

// ---------------- routing: single block, LDS atomics only ----------------
__global__ void route_k(const int* __restrict__ tassign, const float2* __restrict__ tprob,
                        int* __restrict__ rtok, float* __restrict__ rwgt,
                        int* __restrict__ counts, int* __restrict__ ebase) {
  __shared__ int h[NEXP];
  __shared__ int cur[NEXP];
  int tid = threadIdx.x;
  if (tid < NEXP) h[tid] = 0;
  __syncthreads();
  for (int t = tid; t < N_TOK; t += 256) {
    int a = tassign[t];
    atomicAdd(&h[a & 255], 1);
    atomicAdd(&h[(a >> 8) & 255], 1);
  }
  __syncthreads();
  if (tid == 0) {
    int b = 0;
    for (int e = 0; e < NEXP; ++e) { counts[e] = h[e]; ebase[e] = b; cur[e] = b; b += h[e]; }
  }
  __syncthreads();
  for (int t = tid; t < N_TOK; t += 256) {
    int a = tassign[t];
    float2 p = tprob[t];
    int p0 = atomicAdd(&cur[a & 255], 1);
    rtok[p0] = t; rwgt[p0] = p.x;
    int p1 = atomicAdd(&cur[(a >> 8) & 255], 1);
    rtok[p1] = t; rwgt[p1] = p.y;
  }
}

// ---------------- aux loss ----------------
__global__ void aux_k(const int* __restrict__ counts, float* __restrict__ out) {
  if (threadIdx.x == 0) {
    float tot = 0.f, c[NEXP];
    for (int e = 0; e < NEXP; ++e) { c[e] = (float)counts[e]; tot += c[e]; }
    float a = 0.f;
    for (int e = 0; e < NEXP; ++e) { float d = c[e] / tot - 0.125f; a += d * d; }
    out[(size_t)N_TOK * DIM] = a;
  }
}

// ---------------- transpose + fp32->bf16; grid (4096 tiles, 3 mats, nexp) ----------------
__global__ void tcvt_k(const float* __restrict__ w1, const float* __restrict__ w2,
                       const float* __restrict__ wp, unsigned short* __restrict__ d1,
                       unsigned short* __restrict__ d2, unsigned short* __restrict__ d3) {
  int tile = blockIdx.x, mat = blockIdx.y;
  size_t eo = (size_t)blockIdx.z * WELEM;
  const float* src; unsigned short* dst; int R, C;
  if (mat == 0)      { src = w1 + eo; dst = d1 + eo; R = DIM; C = HID; }
  else if (mat == 1) { src = w2 + eo; dst = d2 + eo; R = DIM; C = HID; }
  else               { src = wp + eo; dst = d3 + eo; R = HID; C = DIM; }
  int tilesC = C >> 5;
  int tr = (tile / tilesC) << 5;
  int tc = (tile % tilesC) << 5;
  __shared__ float tl[32][33];
  int tx = threadIdx.x & 31, ty = threadIdx.x >> 5;
#pragma unroll
  for (int i = 0; i < 32; i += 8) tl[ty + i][tx] = src[(size_t)(tr + ty + i) * C + tc + tx];
  __syncthreads();
#pragma unroll
  for (int i = 0; i < 32; i += 8) dst[(size_t)(tc + ty + i) * R + tr + tx] = f2bf(tl[tx][ty + i]);
}

// ================= gemm12m: fused dual-B, dbuf + counted-vmcnt =================
// BM=128 slots, BN=64 (h1+h2), BK=64; 256 thr / 4 waves (2M x 2N).
// acc 64 AGPR + ~60 VGPR; LDS 64KB dbuf -> 2 blk/CU; loads never drain (T4).
template<int DUMMY>
__global__ __launch_bounds__(256, 2) void gemm12m_k(
    const unsigned short* __restrict__ xb,
    const unsigned short* __restrict__ w1b, const unsigned short* __restrict__ w2b,
    const float* __restrict__ b1, const float* __restrict__ b2,
    const int* __restrict__ rtok, const int* __restrict__ counts,
    const int* __restrict__ ebase, const int* __restrict__ gbase,
    unsigned short* __restrict__ Gx, int e0) {
  int f = blockIdx.x + gridDim.x * (blockIdx.y + gridDim.y * blockIdx.z);
  int total = gridDim.x * gridDim.y * gridDim.z;
  int cpx = total >> 3;
  int nf = (f & 7) * cpx + (f >> 3);
  int pe = gridDim.x * gridDim.y;      // 32*64 = 2048
  int ez = nf / pe;
  int r  = nf - ez * pe;
  int ntb = r >> 5;                    // [0,64)
  int mt  = r & 31;                    // [0,32)

  const int e = e0 + ez;
  const int ce = counts[e];
  if (mt * 128 >= ce) return;
  const int rb = ebase[e];
  const int gb_ = gbase[e];
  const unsigned short* w1t = w1b + (size_t)ez * WELEM;
  const unsigned short* w2t = w2b + (size_t)ez * WELEM;
  const float* b1e = b1 + (size_t)e * HID;
  const float* b2e = b2 + (size_t)e * HID;

  __shared__ __attribute__((aligned(16))) unsigned short sA[2][128 * 64];
  __shared__ __attribute__((aligned(16))) unsigned short sB1[2][64 * 64];
  __shared__ __attribute__((aligned(16))) unsigned short sB2[2][64 * 64];

  const int tid = threadIdx.x;
  const int lane = tid & 63, wid = tid >> 6;
  const int wm = wid >> 1, wn = wid & 1;
  const unsigned stg = (unsigned)(wid * 1024);

  const int grow = tid >> 3;
  const int lcol = ((tid & 7) ^ (grow & 7)) << 3;
  int sl0 = mt * 128 + grow;
  int c0 = sl0 < ce ? sl0 : ce - 1;
  int c1 = sl0 + 32 < ce ? sl0 + 32 : ce - 1;
  int c2 = sl0 + 64 < ce ? sl0 + 64 : ce - 1;
  int c3 = sl0 + 96 < ce ? sl0 + 96 : ce - 1;
  const unsigned short* pa0 = xb + (size_t)rtok[rb + c0] * DIM + lcol;
  const unsigned short* pa1 = xb + (size_t)rtok[rb + c1] * DIM + lcol;
  const unsigned short* pa2 = xb + (size_t)rtok[rb + c2] * DIM + lcol;
  const unsigned short* pa3 = xb + (size_t)rtok[rb + c3] * DIM + lcol;
  const unsigned short* pq1 = w1t + (size_t)(ntb * 64 + grow) * DIM + lcol;
  const unsigned short* pq2 = w2t + (size_t)(ntb * 64 + grow) * DIM + lcol;

  f32x4 acc1[4][2] = {};
  f32x4 acc2[4][2] = {};

#define STAGE12(BUF, K0)                                            \
  gload16(pa0 + (K0), (char*)sA[BUF] + stg);                        \
  gload16(pa1 + (K0), (char*)sA[BUF] + stg + 4096);                 \
  gload16(pa2 + (K0), (char*)sA[BUF] + stg + 8192);                 \
  gload16(pa3 + (K0), (char*)sA[BUF] + stg + 12288);                \
  gload16(pq1 + (K0), (char*)sB1[BUF] + stg);                       \
  gload16(pq1 + (K0) + 32 * DIM, (char*)sB1[BUF] + stg + 4096);     \
  gload16(pq2 + (K0), (char*)sB2[BUF] + stg);                       \
  gload16(pq2 + (K0) + 32 * DIM, (char*)sB2[BUF] + stg + 4096);

#define CMP12(BUF)                                                  \
  {                                                                 \
    _Pragma("unroll")                                               \
    for (int s = 0; s < 2; ++s) {                                   \
      short8v af[4], bf1[2], bf2[2];                                \
      _Pragma("unroll")                                             \
      for (int m = 0; m < 4; ++m) {                                 \
        int row = wm * 64 + m * 16 + (lane & 15);                   \
        int p = (s * 4 + (lane >> 4)) ^ (row & 7);                  \
        af[m] = *(const short8v*)((const char*)sA[BUF] + row * 128 + p * 16); \
      }                                                             \
      _Pragma("unroll")                                             \
      for (int n = 0; n < 2; ++n) {                                 \
        int row = wn * 32 + n * 16 + (lane & 15);                   \
        int p = (s * 4 + (lane >> 4)) ^ (row & 7);                  \
        bf1[n] = *(const short8v*)((const char*)sB1[BUF] + row * 128 + p * 16); \
        bf2[n] = *(const short8v*)((const char*)sB2[BUF] + row * 128 + p * 16); \
      }                                                             \
      _Pragma("unroll")                                             \
      for (int m = 0; m < 4; ++m)                                   \
        _Pragma("unroll")                                           \
        for (int n = 0; n < 2; ++n) {                               \
          acc1[m][n] = __builtin_amdgcn_mfma_f32_16x16x32_bf16(af[m], bf1[n], acc1[m][n], 0, 0, 0); \
          acc2[m][n] = __builtin_amdgcn_mfma_f32_16x16x32_bf16(af[m], bf2[n], acc2[m][n], 0, 0, 0); \
        }                                                           \
    }                                                               \
  }

  STAGE12(0, 0);
#pragma unroll 1
  for (int i = 0; i < 7; ++i) {
    STAGE12(1, (2 * i + 1) * 64);
    VMW8; BARR;
    CMP12(0);
    BARR;
    STAGE12(0, (2 * i + 2) * 64);
    VMW8; BARR;
    CMP12(1);
    BARR;
  }
  STAGE12(1, 15 * 64);
  VMW8; BARR;
  CMP12(0);          // tile 14
  VMW0; BARR;
  CMP12(1);          // tile 15
#undef STAGE12
#undef CMP12

#pragma unroll
  for (int n = 0; n < 2; ++n) {
    int col = ntb * 64 + wn * 32 + n * 16 + (lane & 15);
    float bb1 = b1e[col], bb2 = b2e[col];
#pragma unroll
    for (int m = 0; m < 4; ++m) {
      int rbase = mt * 128 + wm * 64 + m * 16 + ((lane >> 4) << 2);
#pragma unroll
      for (int r2 = 0; r2 < 4; ++r2) {
        int slot = rbase + r2;
        if (slot < ce) {
          float h1 = acc1[m][n][r2] + bb1;
          float h2 = acc2[m][n][r2] + bb2;
          float sg = 1.0f / (1.0f + __expf(-h1));
          Gx[(size_t)(gb_ + slot) * HID + col] = f2bf(h1 * sg * h2);
        }
      }
    }
  }
}

// ================= gemm3n: dbuf + counted-vmcnt, K=4096 =================
// BM=128, BN=128, BK=64; grid (32 mt, 8 ntb, NEXP)
__global__ __launch_bounds__(256, 2) void gemm3n_k(
    const unsigned short* __restrict__ Gx, const unsigned short* __restrict__ wpb,
    const float* __restrict__ bp, const int* __restrict__ rtok,
    const float* __restrict__ rwgt, const int* __restrict__ counts,
    const int* __restrict__ ebase, const int* __restrict__ gbase,
    float* __restrict__ out, int e0) {
  int f = blockIdx.x + gridDim.x * (blockIdx.y + gridDim.y * blockIdx.z);
  int total = gridDim.x * gridDim.y * gridDim.z;
  int cpx = total >> 3;
  int nf = (f & 7) * cpx + (f >> 3);
  int pe = gridDim.x * gridDim.y;      // 32*8 = 256
  int ez = nf / pe;
  int r  = nf - ez * pe;
  int ntb = r >> 5;                    // [0,8)
  int mt  = r & 31;                    // [0,32)

  const int e = e0 + ez;
  const int ce = counts[e];
  if (mt * 128 >= ce) return;
  const int rb = ebase[e];
  const int gb_ = gbase[e];
  const unsigned short* wpt = wpb + (size_t)ez * WELEM;
  const float* bpe = bp + (size_t)e * DIM;

  __shared__ __attribute__((aligned(16))) unsigned short sA[2][128 * 64];
  __shared__ __attribute__((aligned(16))) unsigned short sB[2][128 * 64];

  const int tid = threadIdx.x;
  const int lane = tid & 63, wid = tid >> 6;
  const int wm = wid >> 1, wn = wid & 1;
  const unsigned stg = (unsigned)(wid * 1024);

  const int grow = tid >> 3;
  const int lcol = ((tid & 7) ^ (grow & 7)) << 3;
  int sl0 = mt * 128 + grow;
  int c0 = sl0 < ce ? sl0 : ce - 1;
  int c1 = sl0 + 32 < ce ? sl0 + 32 : ce - 1;
  int c2 = sl0 + 64 < ce ? sl0 + 64 : ce - 1;
  int c3 = sl0 + 96 < ce ? sl0 + 96 : ce - 1;
  const unsigned short* pa0 = Gx + (size_t)(gb_ + c0) * HID + lcol;
  const unsigned short* pa1 = Gx + (size_t)(gb_ + c1) * HID + lcol;
  const unsigned short* pa2 = Gx + (size_t)(gb_ + c2) * HID + lcol;
  const unsigned short* pa3 = Gx + (size_t)(gb_ + c3) * HID + lcol;
  const unsigned short* pb0 = wpt + (size_t)(ntb * 128 + grow) * HID + lcol;
  const unsigned short* pb1 = pb0 + (size_t)32 * HID;
  const unsigned short* pb2 = pb0 + (size_t)64 * HID;
  const unsigned short* pb3 = pb0 + (size_t)96 * HID;

  f32x4 acc[4][4] = {};

#define STG3(BUF, K0)                                               \
  gload16(pa0 + (K0), (char*)sA[BUF] + stg);                        \
  gload16(pa1 + (K0), (char*)sA[BUF] + stg + 4096);                 \
  gload16(pa2 + (K0), (char*)sA[BUF] + stg + 8192);                 \
  gload16(pa3 + (K0), (char*)sA[BUF] + stg + 12288);                \
  gload16(pb0 + (K0), (char*)sB[BUF] + stg);                        \
  gload16(pb1 + (K0), (char*)sB[BUF] + stg + 4096);                 \
  gload16(pb2 + (K0), (char*)sB[BUF] + stg + 8192);                 \
  gload16(pb3 + (K0), (char*)sB[BUF] + stg + 12288);

#define CMP3(BUF)                                                   \
  {                                                                 \
    _Pragma("unroll")                                               \
    for (int s = 0; s < 2; ++s) {                                   \
      short8v af[4], bf[4];                                         \
      _Pragma("unroll")                                             \
      for (int m = 0; m < 4; ++m) {                                 \
        int row = wm * 64 + m * 16 + (lane & 15);                   \
        int p = (s * 4 + (lane >> 4)) ^ (row & 7);                  \
        af[m] = *(const short8v*)((const char*)sA[BUF] + row * 128 + p * 16); \
      }                                                             \
      _Pragma("unroll")                                             \
      for (int n = 0; n < 4; ++n) {                                 \
        int row = wn * 64 + n * 16 + (lane & 15);                   \
        int p = (s * 4 + (lane >> 4)) ^ (row & 7);                  \
        bf[n] = *(const short8v*)((const char*)sB[BUF] + row * 128 + p * 16); \
      }                                                             \
      _Pragma("unroll")                                             \
      for (int m = 0; m < 4; ++m)                                   \
        _Pragma("unroll")                                           \
        for (int n = 0; n < 4; ++n)                                 \
          acc[m][n] = __builtin_amdgcn_mfma_f32_16x16x32_bf16(af[m], bf[n], acc[m][n], 0, 0, 0); \
    }                                                               \
  }

  STG3(0, 0);
#pragma unroll 1
  for (int i = 0; i < 31; ++i) {
    STG3(1, (2 * i + 1) * 64);
    VMW8; BARR;
    CMP3(0);
    BARR;
    STG3(0, (2 * i + 2) * 64);
    VMW8; BARR;
    CMP3(1);
    BARR;
  }
  STG3(1, 63 * 64);
  VMW8; BARR;
  CMP3(0);           // tile 62
  VMW0; BARR;
  CMP3(1);           // tile 63
#undef STG3
#undef CMP3

#pragma unroll
  for (int n = 0; n < 4; ++n) {
    int col = ntb * 128 + wn * 64 + n * 16 + (lane & 15);
    float bb = bpe[col];
#pragma unroll
    for (int m = 0; m < 4; ++m) {
      int rbase = mt * 128 + wm * 64 + m * 16 + ((lane >> 4) << 2);
#pragma unroll
      for (int r2 = 0; r2 < 4; ++r2) {
        int slot = rbase + r2;
        if (slot < ce) {
          int tok = rtok[rb + slot];
          float w = rwgt[rb + slot];
          atomicAdd(out + (size_t)tok * DIM + col, w * (acc[m][n][r2] + bb));
        }
      }
    }
  }
}

// ---------------- host ----------------
extern "C" void kernel_launch(void* const* d_in, const int* in_sizes, int n_in,
                              void* d_out, int out_size, void* d_ws, size_t ws_size,
                              hipStream_t stream) {
  const float* x  = (const float*)d_in[0];
  const float* gw = (const float*)d_in[1];
  const float* gb = (const float*)d_in[2];
  const float* w1 = (const float*)d_in[3];
  const float* b1 = (const float*)d_in[4];
  const float* w2 = (const float*)d_in[5];
  const float* b2 = (const float*)d_in[6];
  const float* wp = (const float*)d_in[7];
  const float* bp = (const float*)d_in[8];
  float* out = (float*)d_out;

  char* ws = (char*)d_ws;
  const size_t BIG_NEED = 352551008ull;
  bool big = ws_size >= BIG_NEED;

  unsigned short* xb = (unsigned short*)ws;                       // 16 MB
  unsigned short *Gp, *w1a, *w2a, *wpa;
  int* tassign; float2* tprob; int* rtok; float* rwgt; int* meta;
  if (big) {
    Gp  = (unsigned short*)(ws + 16777216);      // 134.2 MB (16384 global slots)
    w1a = (unsigned short*)(ws + 150994944);     // 64 MB
    w2a = (unsigned short*)(ws + 218103808);     // 64 MB
    wpa = (unsigned short*)(ws + 285212672);     // 64 MB
    tassign = (int*)(ws + 352321536);
    tprob   = (float2*)(ws + 352354304);
    rtok    = (int*)(ws + 352419840);
    rwgt    = (float*)(ws + 352485376);
    meta    = (int*)(ws + 352550912);            // counts[8], ebase[8], zbase[8]
  } else {
    Gp  = (unsigned short*)(ws + 16777216);      // 64 MB (local slots)
    w1a = (unsigned short*)(ws + 83886080);      // 8 MB per-expert
    w2a = (unsigned short*)(ws + 92274688);
    wpa = (unsigned short*)(ws + 100663296);
    tassign = (int*)(ws + 109051904);
    tprob   = (float2*)(ws + 109084672);
    rtok    = (int*)(ws + 109150208);
    rwgt    = (float*)(ws + 109215744);
    meta    = (int*)(ws + 109281280);
  }
  int* counts = meta;
  int* ebase  = meta + 8;
  int* zbase  = meta + 16;

  hipMemsetAsync(meta, 0, 96, stream);
  hipMemsetAsync(out, 0, (size_t)(N_TOK * DIM + 1) * sizeof(float), stream);

  convert_x_k<<<4096, 256, 0, stream>>>(x, xb);
  gate2_k<<<N_TOK / 4, 256, 0, stream>>>(x, gw, gb, tassign, tprob);
  route_k<<<1, 256, 0, stream>>>(tassign, tprob, rtok, rwgt, counts, ebase);
  aux_k<<<1, 64, 0, stream>>>(counts, out);

  if (big) {
    tcvt_k<<<dim3(4096, 3, NEXP), 256, 0, stream>>>(w1, w2, wp, w1a, w2a, wpa);
    gemm12m_k<0><<<dim3(32, 64, NEXP), 256, 0, stream>>>(
        xb, w1a, w2a, b1, b2, rtok, counts, ebase, ebase, Gp, 0);
    gemm3n_k<<<dim3(32, 8, NEXP), 256, 0, stream>>>(
        Gp, wpa, bp, rtok, rwgt, counts, ebase, ebase, out, 0);
  } else {
    for (int e = 0; e < NEXP; ++e) {
      tcvt_k<<<dim3(4096, 3, 1), 256, 0, stream>>>(
          w1 + (size_t)e * WELEM, w2 + (size_t)e * WELEM, wp + (size_t)e * WELEM,
          w1a, w2a, wpa);
      gemm12m_k<0><<<dim3(32, 64, 1), 256, 0, stream>>>(
          xb, w1a, w2a, b1, b2, rtok, counts, ebase, zbase, Gp, e);
      gemm3n_k<<<dim3(32, 8, 1), 256, 0, stream>>>(
          Gp, wpa, bp, rtok, rwgt, counts, ebase, zbase, out, e);
    }
  }
}

// Round 15
// 805.565 us; speedup vs baseline: 1.3100x; 1.3100x over previous
//
#include <hip/hip_runtime.h>
#include <cstdint>
#include <cstddef>

#define N_TOK 8192
#define DIM   1024
#define NEXP  8
#define HID   4096
#define WELEM 4194304ull   // D*H elements per expert matrix

typedef __attribute__((ext_vector_type(8))) short short8v;
typedef __attribute__((ext_vector_type(8))) unsigned short ushort8v;
typedef __attribute__((ext_vector_type(4))) unsigned short ushort4v;
typedef __attribute__((ext_vector_type(4))) float f32x4;

__device__ __forceinline__ unsigned short f2bf(float f) {
  unsigned u = __builtin_bit_cast(unsigned, f);
  u += 0x7fffu + ((u >> 16) & 1u);     // RNE
  return (unsigned short)(u >> 16);
}

__device__ __forceinline__ void gload16(const void* g, void* l) {
  __builtin_amdgcn_global_load_lds(
      (const __attribute__((address_space(1))) void*)g,
      (__attribute__((address_space(3))) void*)l, 16, 0, 0);
}

// ---------------- gate (+ fused x fp32->bf16 convert) ----------------
__global__ void gate2_k(const float* __restrict__ x, const float* __restrict__ gw,
                        const float* __restrict__ gb, int* __restrict__ tassign,
                        float2* __restrict__ tprob, unsigned short* __restrict__ xb) {
  int lane = threadIdx.x & 63, wid = threadIdx.x >> 6;
  int t = blockIdx.x * 4 + wid;
  const float* xr = x + (size_t)t * DIM;
  unsigned short* xbr = xb + (size_t)t * DIM;
  float acc[NEXP];
#pragma unroll
  for (int e = 0; e < NEXP; ++e) acc[e] = 0.f;
#pragma unroll
  for (int j = 0; j < DIM / 256; ++j) {
    int d0 = j * 256 + lane * 4;
    float4 xv = *(const float4*)(xr + d0);
    ushort4v o;
    o[0] = f2bf(xv.x); o[1] = f2bf(xv.y); o[2] = f2bf(xv.z); o[3] = f2bf(xv.w);
    *(ushort4v*)(xbr + d0) = o;
    const float* gp = gw + (size_t)d0 * NEXP;
#pragma unroll
    for (int c = 0; c < 4; ++c) {
      float xs = (c == 0) ? xv.x : (c == 1) ? xv.y : (c == 2) ? xv.z : xv.w;
      float4 g0 = *(const float4*)(gp + c * NEXP);
      float4 g1 = *(const float4*)(gp + c * NEXP + 4);
      acc[0] += xs * g0.x; acc[1] += xs * g0.y; acc[2] += xs * g0.z; acc[3] += xs * g0.w;
      acc[4] += xs * g1.x; acc[5] += xs * g1.y; acc[6] += xs * g1.z; acc[7] += xs * g1.w;
    }
  }
#pragma unroll
  for (int e = 0; e < NEXP; ++e) {
    float v = acc[e];
#pragma unroll
    for (int s = 1; s < 64; s <<= 1) v += __shfl_xor(v, s);
    acc[e] = v;
  }
  if (lane == 0) {
    float lg[NEXP];
#pragma unroll
    for (int e = 0; e < NEXP; ++e) lg[e] = acc[e] + gb[e];
    int i0 = 0;
#pragma unroll
    for (int e = 1; e < NEXP; ++e) if (lg[e] > lg[i0]) i0 = e;
    int i1 = -1;
#pragma unroll
    for (int e = 0; e < NEXP; ++e) if (e != i0 && (i1 < 0 || lg[e] > lg[i1])) i1 = e;
    float ex = expf(lg[i1] - lg[i0]);       // <= 1
    float p0 = 1.f / (1.f + ex);
    float p1 = ex * p0;
    tassign[t] = i0 | (i1 << 8);
    tprob[t] = make_float2(p0, p1);
  }
}

// ---------------- routing: single block, LDS atomics only ----------------
__global__ void route_k(const int* __restrict__ tassign, const float2* __restrict__ tprob,
                        int* __restrict__ rtok, float* __restrict__ rwgt,
                        int* __restrict__ counts, int* __restrict__ ebase) {
  __shared__ int h[NEXP];
  __shared__ int cur[NEXP];
  int tid = threadIdx.x;
  if (tid < NEXP) h[tid] = 0;
  __syncthreads();
  for (int t = tid; t < N_TOK; t += 256) {
    int a = tassign[t];
    atomicAdd(&h[a & 255], 1);
    atomicAdd(&h[(a >> 8) & 255], 1);
  }
  __syncthreads();
  if (tid == 0) {
    int b = 0;
    for (int e = 0; e < NEXP; ++e) { counts[e] = h[e]; ebase[e] = b; cur[e] = b; b += h[e]; }
  }
  __syncthreads();
  for (int t = tid; t < N_TOK; t += 256) {
    int a = tassign[t];
    float2 p = tprob[t];
    int p0 = atomicAdd(&cur[a & 255], 1);
    rtok[p0] = t; rwgt[p0] = p.x;
    int p1 = atomicAdd(&cur[(a >> 8) & 255], 1);
    rtok[p1] = t; rwgt[p1] = p.y;
  }
}

// ---------------- aux loss ----------------
__global__ void aux_k(const int* __restrict__ counts, float* __restrict__ out) {
  if (threadIdx.x == 0) {
    float tot = 0.f, c[NEXP];
    for (int e = 0; e < NEXP; ++e) { c[e] = (float)counts[e]; tot += c[e]; }
    float a = 0.f;
    for (int e = 0; e < NEXP; ++e) { float d = c[e] / tot - 0.125f; a += d * d; }
    out[(size_t)N_TOK * DIM] = a;
  }
}

// ------- transpose + fp32->bf16, 64x64 tiles, vectorized both sides -------
// load float4 (16B/lane), store ushort8 (16B/lane); grid (1024, 3, NEXP)
__global__ void tcvt_k(const float* __restrict__ w1, const float* __restrict__ w2,
                       const float* __restrict__ wp, unsigned short* __restrict__ d1,
                       unsigned short* __restrict__ d2, unsigned short* __restrict__ d3) {
  int tile = blockIdx.x, mat = blockIdx.y;
  size_t eo = (size_t)blockIdx.z * WELEM;
  const float* src; unsigned short* dst; int R, C;
  if (mat == 0)      { src = w1 + eo; dst = d1 + eo; R = DIM; C = HID; }
  else if (mat == 1) { src = w2 + eo; dst = d2 + eo; R = DIM; C = HID; }
  else               { src = wp + eo; dst = d3 + eo; R = HID; C = DIM; }
  int tilesC = C >> 6;
  int tr = (tile / tilesC) << 6;
  int tc = (tile % tilesC) << 6;
  __shared__ float tl[64][65];
  int tid = threadIdx.x;
  int lr = tid >> 4;                 // 0..15
  int lc = (tid & 15) << 2;          // 0,4,...,60
#pragma unroll
  for (int i = 0; i < 4; ++i) {
    float4 v = *(const float4*)(src + (size_t)(tr + lr + i * 16) * C + tc + lc);
    tl[lr + i * 16][lc]     = v.x;
    tl[lr + i * 16][lc + 1] = v.y;
    tl[lr + i * 16][lc + 2] = v.z;
    tl[lr + i * 16][lc + 3] = v.w;
  }
  __syncthreads();
  int oc = tid >> 3;                 // 0..31
  int orr = (tid & 7) << 3;          // 0,8,...,56
#pragma unroll
  for (int i = 0; i < 2; ++i) {
    int c = oc + i * 32;
    ushort8v v;
#pragma unroll
    for (int k = 0; k < 8; ++k) v[k] = f2bf(tl[orr + k][c]);
    *(ushort8v*)(dst + (size_t)(tc + c) * R + tr + orr) = v;
  }
}

// ================= gemm12m: fused dual-B, m97 structure =================
// BM=128 slots, BN=64 (h1+h2), BK=64; 256 thr / 4 waves (2M x 2N).
// acc 64 AGPR + ~60 VGPR = 124 <= 128 cap at (256,4); LDS 32KB single-buffered
// -> 4 blocks/CU. Per K-step: sync -> STAGE(A,B1,B2) -> sync -> CMP. (m97 form)
template<int DUMMY>
__global__ __launch_bounds__(256, 4) void gemm12m_k(
    const unsigned short* __restrict__ xb,
    const unsigned short* __restrict__ w1b, const unsigned short* __restrict__ w2b,
    const float* __restrict__ b1, const float* __restrict__ b2,
    const int* __restrict__ rtok, const int* __restrict__ counts,
    const int* __restrict__ ebase, const int* __restrict__ gbase,
    unsigned short* __restrict__ Gx, int e0) {
  int f = blockIdx.x + gridDim.x * (blockIdx.y + gridDim.y * blockIdx.z);
  int total = gridDim.x * gridDim.y * gridDim.z;
  int cpx = total >> 3;
  int nf = (f & 7) * cpx + (f >> 3);
  int pe = gridDim.x * gridDim.y;      // 32*64 = 2048
  int ez = nf / pe;
  int r  = nf - ez * pe;
  int ntb = r >> 5;                    // [0,64)
  int mt  = r & 31;                    // [0,32)

  const int e = e0 + ez;
  const int ce = counts[e];
  if (mt * 128 >= ce) return;
  const int rb = ebase[e];
  const int gb_ = gbase[e];
  const unsigned short* w1t = w1b + (size_t)ez * WELEM;
  const unsigned short* w2t = w2b + (size_t)ez * WELEM;
  const float* b1e = b1 + (size_t)e * HID;
  const float* b2e = b2 + (size_t)e * HID;

  __shared__ __attribute__((aligned(16))) unsigned short sA[128 * 64];
  __shared__ __attribute__((aligned(16))) unsigned short sB1[64 * 64];
  __shared__ __attribute__((aligned(16))) unsigned short sB2[64 * 64];

  const int tid = threadIdx.x;
  const int lane = tid & 63, wid = tid >> 6;
  const int wm = wid >> 1, wn = wid & 1;
  const unsigned stg = (unsigned)(wid * 1024);

  const int grow = tid >> 3;
  const int lcol = ((tid & 7) ^ (grow & 7)) << 3;
  int sl0 = mt * 128 + grow;
  int c0 = sl0 < ce ? sl0 : ce - 1;
  int c1 = sl0 + 32 < ce ? sl0 + 32 : ce - 1;
  int c2 = sl0 + 64 < ce ? sl0 + 64 : ce - 1;
  int c3 = sl0 + 96 < ce ? sl0 + 96 : ce - 1;
  const unsigned short* pa0 = xb + (size_t)rtok[rb + c0] * DIM + lcol;
  const unsigned short* pa1 = xb + (size_t)rtok[rb + c1] * DIM + lcol;
  const unsigned short* pa2 = xb + (size_t)rtok[rb + c2] * DIM + lcol;
  const unsigned short* pa3 = xb + (size_t)rtok[rb + c3] * DIM + lcol;
  const unsigned short* pq1 = w1t + (size_t)(ntb * 64 + grow) * DIM + lcol;
  const unsigned short* pq2 = w2t + (size_t)(ntb * 64 + grow) * DIM + lcol;

  f32x4 acc1[4][2] = {};
  f32x4 acc2[4][2] = {};

#pragma unroll 1
  for (int t = 0; t < 16; ++t) {
    const int k0 = t * 64;
    __syncthreads();
    gload16(pa0 + k0, (char*)sA + stg);
    gload16(pa1 + k0, (char*)sA + stg + 4096);
    gload16(pa2 + k0, (char*)sA + stg + 8192);
    gload16(pa3 + k0, (char*)sA + stg + 12288);
    gload16(pq1 + k0, (char*)sB1 + stg);
    gload16(pq1 + k0 + 32 * DIM, (char*)sB1 + stg + 4096);
    gload16(pq2 + k0, (char*)sB2 + stg);
    gload16(pq2 + k0 + 32 * DIM, (char*)sB2 + stg + 4096);
    __syncthreads();
#pragma unroll
    for (int s = 0; s < 2; ++s) {
      short8v af[4], bf1[2], bf2[2];
#pragma unroll
      for (int m = 0; m < 4; ++m) {
        int row = wm * 64 + m * 16 + (lane & 15);
        int p = (s * 4 + (lane >> 4)) ^ (row & 7);
        af[m] = *(const short8v*)((const char*)sA + row * 128 + p * 16);
      }
#pragma unroll
      for (int n = 0; n < 2; ++n) {
        int row = wn * 32 + n * 16 + (lane & 15);
        int p = (s * 4 + (lane >> 4)) ^ (row & 7);
        bf1[n] = *(const short8v*)((const char*)sB1 + row * 128 + p * 16);
        bf2[n] = *(const short8v*)((const char*)sB2 + row * 128 + p * 16);
      }
#pragma unroll
      for (int m = 0; m < 4; ++m)
#pragma unroll
        for (int n = 0; n < 2; ++n) {
          acc1[m][n] = __builtin_amdgcn_mfma_f32_16x16x32_bf16(af[m], bf1[n], acc1[m][n], 0, 0, 0);
          acc2[m][n] = __builtin_amdgcn_mfma_f32_16x16x32_bf16(af[m], bf2[n], acc2[m][n], 0, 0, 0);
        }
    }
  }

#pragma unroll
  for (int n = 0; n < 2; ++n) {
    int col = ntb * 64 + wn * 32 + n * 16 + (lane & 15);
    float bb1 = b1e[col], bb2 = b2e[col];
#pragma unroll
    for (int m = 0; m < 4; ++m) {
      int rbase = mt * 128 + wm * 64 + m * 16 + ((lane >> 4) << 2);
#pragma unroll
      for (int r2 = 0; r2 < 4; ++r2) {
        int slot = rbase + r2;
        if (slot < ce) {
          float h1 = acc1[m][n][r2] + bb1;
          float h2 = acc2[m][n][r2] + bb2;
          float sg = 1.0f / (1.0f + __expf(-h1));
          Gx[(size_t)(gb_ + slot) * HID + col] = f2bf(h1 * sg * h2);
        }
      }
    }
  }
}

// ================= 128x128 m97-structure GEMM core (gemm3n) =================
#define STG(SD, P0, P1, P2, P3, K0)                                 \
  gload16(P0 + (K0), (char*)SD + stg);                              \
  gload16(P1 + (K0), (char*)SD + stg + 4096);                       \
  gload16(P2 + (K0), (char*)SD + stg + 8192);                       \
  gload16(P3 + (K0), (char*)SD + stg + 12288);

#define CMP()                                                       \
  {                                                                 \
    _Pragma("unroll")                                               \
    for (int s = 0; s < 2; ++s) {                                   \
      short8v af[4], bf[4];                                         \
      _Pragma("unroll")                                             \
      for (int m = 0; m < 4; ++m) {                                 \
        int row = wm * 64 + m * 16 + (lane & 15);                   \
        int p = (s * 4 + (lane >> 4)) ^ (row & 7);                  \
        af[m] = *(const short8v*)((const char*)sA + row * 128 + p * 16); \
      }                                                             \
      _Pragma("unroll")                                             \
      for (int n = 0; n < 4; ++n) {                                 \
        int row = wn * 64 + n * 16 + (lane & 15);                   \
        int p = (s * 4 + (lane >> 4)) ^ (row & 7);                  \
        bf[n] = *(const short8v*)((const char*)sB + row * 128 + p * 16); \
      }                                                             \
      _Pragma("unroll")                                             \
      for (int m = 0; m < 4; ++m)                                   \
        _Pragma("unroll")                                           \
        for (int n = 0; n < 4; ++n)                                 \
          acc[m][n] = __builtin_amdgcn_mfma_f32_16x16x32_bf16(af[m], bf[n], acc[m][n], 0, 0, 0); \
    }                                                               \
  }

#define GEMM_LOOP(NTILE)                                            \
  _Pragma("unroll 1")                                               \
  for (int t = 0; t < (NTILE); ++t) {                               \
    __syncthreads();                                                \
    STG(sA, pa0, pa1, pa2, pa3, t * 64);                            \
    STG(sB, pb0, pb1, pb2, pb3, t * 64);                            \
    __syncthreads();                                                \
    CMP();                                                          \
  }

// ---------------- gemm3n: out[token] += w*(G@Wp^T + bp), K=4096 ----------------
// grid (32 mt, 8 ntb, NEXP)
__global__ __launch_bounds__(256, 4) void gemm3n_k(
    const unsigned short* __restrict__ Gx, const unsigned short* __restrict__ wpb,
    const float* __restrict__ bp, const int* __restrict__ rtok,
    const float* __restrict__ rwgt, const int* __restrict__ counts,
    const int* __restrict__ ebase, const int* __restrict__ gbase,
    float* __restrict__ out, int e0) {
  int f = blockIdx.x + gridDim.x * (blockIdx.y + gridDim.y * blockIdx.z);
  int total = gridDim.x * gridDim.y * gridDim.z;
  int cpx = total >> 3;
  int nf = (f & 7) * cpx + (f >> 3);
  int pe = gridDim.x * gridDim.y;      // 32*8 = 256
  int ez = nf / pe;
  int r  = nf - ez * pe;
  int ntb = r >> 5;                    // [0,8)
  int mt  = r & 31;                    // [0,32)

  const int e = e0 + ez;
  const int ce = counts[e];
  if (mt * 128 >= ce) return;
  const int rb = ebase[e];
  const int gb_ = gbase[e];
  const unsigned short* wpt = wpb + (size_t)ez * WELEM;
  const float* bpe = bp + (size_t)e * DIM;

  __shared__ __attribute__((aligned(16))) unsigned short sA[128 * 64];
  __shared__ __attribute__((aligned(16))) unsigned short sB[128 * 64];

  const int tid = threadIdx.x;
  const int lane = tid & 63, wid = tid >> 6;
  const int wm = wid >> 1, wn = wid & 1;
  const unsigned stg = (unsigned)(wid * 1024);

  const int grow = tid >> 3;
  const int lcol = ((tid & 7) ^ (grow & 7)) << 3;
  int sl0 = mt * 128 + grow;
  int c0 = sl0 < ce ? sl0 : ce - 1;
  int c1 = sl0 + 32 < ce ? sl0 + 32 : ce - 1;
  int c2 = sl0 + 64 < ce ? sl0 + 64 : ce - 1;
  int c3 = sl0 + 96 < ce ? sl0 + 96 : ce - 1;
  const unsigned short* pa0 = Gx + (size_t)(gb_ + c0) * HID + lcol;
  const unsigned short* pa1 = Gx + (size_t)(gb_ + c1) * HID + lcol;
  const unsigned short* pa2 = Gx + (size_t)(gb_ + c2) * HID + lcol;
  const unsigned short* pa3 = Gx + (size_t)(gb_ + c3) * HID + lcol;
  const unsigned short* pb0 = wpt + (size_t)(ntb * 128 + grow) * HID + lcol;
  const unsigned short* pb1 = pb0 + (size_t)32 * HID;
  const unsigned short* pb2 = pb0 + (size_t)64 * HID;
  const unsigned short* pb3 = pb0 + (size_t)96 * HID;

  f32x4 acc[4][4] = {};
  GEMM_LOOP(64);   // K = 4096

#pragma unroll
  for (int n = 0; n < 4; ++n) {
    int col = ntb * 128 + wn * 64 + n * 16 + (lane & 15);
    float bb = bpe[col];
#pragma unroll
    for (int m = 0; m < 4; ++m) {
      int rbase = mt * 128 + wm * 64 + m * 16 + ((lane >> 4) << 2);
#pragma unroll
      for (int r2 = 0; r2 < 4; ++r2) {
        int slot = rbase + r2;
        if (slot < ce) {
          int tok = rtok[rb + slot];
          float w = rwgt[rb + slot];
          atomicAdd(out + (size_t)tok * DIM + col, w * (acc[m][n][r2] + bb));
        }
      }
    }
  }
}

// ---------------- host ----------------
extern "C" void kernel_launch(void* const* d_in, const int* in_sizes, int n_in,
                              void* d_out, int out_size, void* d_ws, size_t ws_size,
                              hipStream_t stream) {
  const float* x  = (const float*)d_in[0];
  const float* gw = (const float*)d_in[1];
  const float* gb = (const float*)d_in[2];
  const float* w1 = (const float*)d_in[3];
  const float* b1 = (const float*)d_in[4];
  const float* w2 = (const float*)d_in[5];
  const float* b2 = (const float*)d_in[6];
  const float* wp = (const float*)d_in[7];
  const float* bp = (const float*)d_in[8];
  float* out = (float*)d_out;

  char* ws = (char*)d_ws;
  const size_t BIG_NEED = 352551008ull;
  bool big = ws_size >= BIG_NEED;

  unsigned short* xb = (unsigned short*)ws;                       // 16 MB
  unsigned short *Gp, *w1a, *w2a, *wpa;
  int* tassign; float2* tprob; int* rtok; float* rwgt; int* meta;
  if (big) {
    Gp  = (unsigned short*)(ws + 16777216);      // 134.2 MB (16384 global slots)
    w1a = (unsigned short*)(ws + 150994944);     // 64 MB
    w2a = (unsigned short*)(ws + 218103808);     // 64 MB
    wpa = (unsigned short*)(ws + 285212672);     // 64 MB
    tassign = (int*)(ws + 352321536);
    tprob   = (float2*)(ws + 352354304);
    rtok    = (int*)(ws + 352419840);
    rwgt    = (float*)(ws + 352485376);
    meta    = (int*)(ws + 352550912);            // counts[8], ebase[8], zbase[8]
  } else {
    Gp  = (unsigned short*)(ws + 16777216);      // 64 MB (local slots)
    w1a = (unsigned short*)(ws + 83886080);      // 8 MB per-expert
    w2a = (unsigned short*)(ws + 92274688);
    wpa = (unsigned short*)(ws + 100663296);
    tassign = (int*)(ws + 109051904);
    tprob   = (float2*)(ws + 109084672);
    rtok    = (int*)(ws + 109150208);
    rwgt    = (float*)(ws + 109215744);
    meta    = (int*)(ws + 109281280);
  }
  int* counts = meta;
  int* ebase  = meta + 8;
  int* zbase  = meta + 16;

  hipMemsetAsync(meta, 0, 96, stream);
  hipMemsetAsync(out, 0, (size_t)(N_TOK * DIM + 1) * sizeof(float), stream);

  gate2_k<<<N_TOK / 4, 256, 0, stream>>>(x, gw, gb, tassign, tprob, xb);
  route_k<<<1, 256, 0, stream>>>(tassign, tprob, rtok, rwgt, counts, ebase);
  aux_k<<<1, 64, 0, stream>>>(counts, out);

  if (big) {
    tcvt_k<<<dim3(1024, 3, NEXP), 256, 0, stream>>>(w1, w2, wp, w1a, w2a, wpa);
    gemm12m_k<0><<<dim3(32, 64, NEXP), 256, 0, stream>>>(
        xb, w1a, w2a, b1, b2, rtok, counts, ebase, ebase, Gp, 0);
    gemm3n_k<<<dim3(32, 8, NEXP), 256, 0, stream>>>(
        Gp, wpa, bp, rtok, rwgt, counts, ebase, ebase, out, 0);
  } else {
    for (int e = 0; e < NEXP; ++e) {
      tcvt_k<<<dim3(1024, 3, 1), 256, 0, stream>>>(
          w1 + (size_t)e * WELEM, w2 + (size_t)e * WELEM, wp + (size_t)e * WELEM,
          w1a, w2a, wpa);
      gemm12m_k<0><<<dim3(32, 64, 1), 256, 0, stream>>>(
          xb, w1a, w2a, b1, b2, rtok, counts, ebase, zbase, Gp, e);
      gemm3n_k<<<dim3(32, 8, 1), 256, 0, stream>>>(
          Gp, wpa, bp, rtok, rwgt, counts, ebase, zbase, out, e);
    }
  }
}